// Round 7
// baseline (475.271 us; speedup 1.0000x reference)
//
#include <hip/hip_runtime.h>

// PPAModel: node encoder (2-layer MLP) -> edge gather/concat -> edge MLP -> sigmoid
// IN=128, HID=256, OUT=128, N_NODES=100000, N_EDGES=1000000
//
// ws layout:
//   [0,256)            : int flag (1 => edge_index stored as int64)
//   [256, +64KB)       : W1 bf16 swizzled  [k/8][n][k%8], K=128,N=256
//   [65792, +64KB)     : W2 bf16 swizzled  K=256,N=128
//   [131328, +128KB)   : W3 bf16 swizzled  K=256,N=256
//   [262400, +25.6MB)  : h table bf16 [100000][128]
//
// edge_mlp v5.1: 4 waves/block, 64 N-cols/wave, W3 slice fully in registers
// (zero global in K-loop). A staged by global_load_lds gather DMA (no data
// regs), XOR-swizzled (0 conflicts). Epilogue reduction via DPP row_shr on
// the VALU pipe — row_shr accumulates toward the HIGH lane, so the full
// 16-lane sum lives in cl==15 (r6 bug: wrote from cl==0).

#define NN 100000
#define NE 1000000
#define NT 15625     // NE/64 edge tiles
#define GRID_E 512
#define GRID_N 512
#define NTN 1563     // node tiles (ceil(100000/64))

typedef __attribute__((ext_vector_type(8))) __bf16 bf16x8;
typedef __attribute__((ext_vector_type(4))) float f32x4;
typedef __attribute__((ext_vector_type(4))) unsigned short us4;

__device__ __forceinline__ unsigned short f2bf(float f) {
    unsigned u = __float_as_uint(f);
    return (unsigned short)((u + 0x7FFFu + ((u >> 16) & 1u)) >> 16);
}

template <int CTRL>
__device__ __forceinline__ float dpp_add(float v) {
    return v + __int_as_float(__builtin_amdgcn_update_dpp(
                   0, __float_as_int(v), CTRL, 0xF, 0xF, true));
}
// sum over the 16 lanes of a DPP row; result valid at (lane&15)==15
__device__ __forceinline__ float row_reduce16(float v) {
    v = dpp_add<0x118>(v);  // row_shr:8  (lane i += lane i-8)
    v = dpp_add<0x114>(v);  // row_shr:4
    v = dpp_add<0x112>(v);  // row_shr:2
    v = dpp_add<0x111>(v);  // row_shr:1
    return v;
}

#define GLD16(g, l)                                                         \
    __builtin_amdgcn_global_load_lds(                                       \
        (__attribute__((address_space(1))) void*)(g),                       \
        (__attribute__((address_space(3))) void*)(l), 16, 0, 0)

// ---------------- prep: swizzle weights to bf16, detect index dtype -------
__global__ void prep_kernel(const float* __restrict__ W1,
                            const float* __restrict__ W2,
                            const float* __restrict__ W3,
                            const void* __restrict__ eidx,
                            unsigned short* __restrict__ w1s,
                            unsigned short* __restrict__ w2s,
                            unsigned short* __restrict__ w3s,
                            int* __restrict__ flag) {
    int t = blockIdx.x * blockDim.x + threadIdx.x;
    if (t < 32768) {                       // W1: K=128, N=256
        int k = t >> 8, n = t & 255;
        w1s[(k >> 3) * 2048 + n * 8 + (k & 7)] = f2bf(W1[t]);
    } else if (t < 65536) {                // W2: K=256, N=128
        int i = t - 32768;
        int k = i >> 7, n = i & 127;
        w2s[(k >> 3) * 1024 + n * 8 + (k & 7)] = f2bf(W2[i]);
    } else if (t < 131072) {               // W3: K=256, N=256
        int i = t - 65536;
        int k = i >> 8, n = i & 255;
        w3s[(k >> 3) * 2048 + n * 8 + (k & 7)] = f2bf(W3[i]);
    }
    if (t == 0) {
        const unsigned* u = (const unsigned*)eidx;
        int all0 = 1;
        for (int i = 0; i < 32; ++i) all0 &= (u[2 * i + 1] == 0u);
        *flag = all0;
    }
}

// ---------------- phase 1: node encoder, persistent, weights in regs ------
__global__ __launch_bounds__(256, 2) void node_enc(
    const float* __restrict__ x, const float* __restrict__ b1,
    const float* __restrict__ b2, const unsigned short* __restrict__ w1s,
    const unsigned short* __restrict__ w2s, unsigned short* __restrict__ hbf) {
    __shared__ __align__(16) unsigned short A1[64 * 136];  // 17408 B
    __shared__ __align__(16) unsigned short A2[64 * 264];  // 33792 B

    const int t = threadIdx.x, lane = t & 63, w = t >> 6;
    const int cl = lane & 15, q = lane >> 4;

    // hoisted weight slices (once per block)
    const int nb = w * 64;
    bf16x8 w1r[4][4];
#pragma unroll
    for (int s = 0; s < 4; ++s)
#pragma unroll
        for (int nt = 0; nt < 4; ++nt)
            w1r[s][nt] = *(const bf16x8*)(w1s + (s * 4 + q) * 2048 +
                                          (nb + nt * 16 + cl) * 8);
    float b1v[4];
#pragma unroll
    for (int nt = 0; nt < 4; ++nt) b1v[nt] = b1[nb + nt * 16 + cl];
    const int nb2 = w * 32;
    bf16x8 w2r[8][2];
#pragma unroll
    for (int s = 0; s < 8; ++s)
#pragma unroll
        for (int nt = 0; nt < 2; ++nt)
            w2r[s][nt] = *(const bf16x8*)(w2s + (s * 4 + q) * 1024 +
                                          (nb2 + nt * 16 + cl) * 8);
    float b2v[2];
#pragma unroll
    for (int nt = 0; nt < 2; ++nt) b2v[nt] = b2[nb2 + nt * 16 + cl];

    for (int tile = blockIdx.x; tile < NTN; tile += GRID_N) {
        const int m0 = tile * 64;
        // stage x rows -> bf16 LDS
        {
            const float4* x4 = (const float4*)x;
#pragma unroll
            for (int i = 0; i < 8; ++i) {
                int lin = i * 256 + t;
                int m = lin >> 5, c = lin & 31;
                int node = m0 + m;
                if (node > NN - 1) node = NN - 1;
                float4 v = x4[node * 32 + c];
                us4 b;
                b.x = f2bf(v.x); b.y = f2bf(v.y); b.z = f2bf(v.z); b.w = f2bf(v.w);
                *(us4*)(A1 + m * 136 + c * 4) = b;
            }
        }
        __syncthreads();

        // GEMM1: [64x128]x[128x256]
        f32x4 acc[4][4];
#pragma unroll
        for (int mt = 0; mt < 4; ++mt)
#pragma unroll
            for (int nt = 0; nt < 4; ++nt)
                acc[mt][nt] = (f32x4){b1v[nt], b1v[nt], b1v[nt], b1v[nt]};
#pragma unroll
        for (int s = 0; s < 4; ++s) {
            bf16x8 a[4];
#pragma unroll
            for (int mt = 0; mt < 4; ++mt)
                a[mt] = *(const bf16x8*)(A1 + (mt * 16 + cl) * 136 + s * 32 + q * 8);
#pragma unroll
            for (int mt = 0; mt < 4; ++mt)
#pragma unroll
                for (int nt = 0; nt < 4; ++nt)
                    acc[mt][nt] = __builtin_amdgcn_mfma_f32_16x16x32_bf16(
                        a[mt], w1r[s][nt], acc[mt][nt], 0, 0, 0);
        }

        // relu -> A2 [m][k] bf16
#pragma unroll
        for (int mt = 0; mt < 4; ++mt)
#pragma unroll
            for (int nt = 0; nt < 4; ++nt)
#pragma unroll
                for (int r = 0; r < 4; ++r) {
                    float v = fmaxf(acc[mt][nt][r], 0.0f);
                    A2[(mt * 16 + q * 4 + r) * 264 + nb + nt * 16 + cl] = f2bf(v);
                }
        __syncthreads();

        // GEMM2: [64x256]x[256x128]
        f32x4 acc2[4][2];
#pragma unroll
        for (int mt = 0; mt < 4; ++mt)
#pragma unroll
            for (int nt = 0; nt < 2; ++nt)
                acc2[mt][nt] = (f32x4){b2v[nt], b2v[nt], b2v[nt], b2v[nt]};
#pragma unroll
        for (int s = 0; s < 8; ++s) {
            bf16x8 a[4];
#pragma unroll
            for (int mt = 0; mt < 4; ++mt)
                a[mt] = *(const bf16x8*)(A2 + (mt * 16 + cl) * 264 + s * 32 + q * 8);
#pragma unroll
            for (int mt = 0; mt < 4; ++mt)
#pragma unroll
                for (int nt = 0; nt < 2; ++nt)
                    acc2[mt][nt] = __builtin_amdgcn_mfma_f32_16x16x32_bf16(
                        a[mt], w2r[s][nt], acc2[mt][nt], 0, 0, 0);
        }
#pragma unroll
        for (int mt = 0; mt < 4; ++mt)
#pragma unroll
            for (int nt = 0; nt < 2; ++nt)
#pragma unroll
                for (int r = 0; r < 4; ++r) {
                    int node = m0 + mt * 16 + q * 4 + r;
                    if (node < NN)
                        hbf[node * 128 + nb2 + nt * 16 + cl] = f2bf(acc2[mt][nt][r]);
                }
        // next iter's A1 write is after sync#2; iter-i A1 reads end before it.
    }
}

// ---------------- phase 2: edge MLP, 4 waves, DMA gather, DPP epilogue ----
__global__ __launch_bounds__(256, 2) void edge_mlp(
    const void* __restrict__ eidx, const unsigned short* __restrict__ hbf,
    const unsigned short* __restrict__ w3s, const float* __restrict__ b3,
    const float* __restrict__ W4, const float* __restrict__ b4,
    const int* __restrict__ flag, float* __restrict__ out) {
    // A: [buf][64 rows][256 k] bf16, row stride 512 B gapless (DMA needs it),
    // 16B chunk phys = logical ^ (row & 15). 2 x 32 KB.
    __shared__ __align__(16) unsigned short A[2][16384];
    __shared__ __align__(16) float partial[2][4][64];

    const int t = threadIdx.x, lane = t & 63, w = t >> 6;  // w: 0..3
    const int cl = lane & 15, q = lane >> 4;
    const bool i64f = (*flag != 0);
    const int* ei32 = (const int*)eidx;
    const long long* ei64 = (const long long*)eidx;

    // W3 slice in registers: wave owns 64 N-cols -> w3r[8][4] (128 VGPRs)
    const int nb = w * 64;
    float b3v[4], w4v[4];
#pragma unroll
    for (int nt = 0; nt < 4; ++nt) {
        int n = nb + nt * 16 + cl;
        b3v[nt] = b3[n];
        w4v[nt] = W4[n];
    }
    const float b4v = b4[0];
    bf16x8 w3r[8][4];
#pragma unroll
    for (int s = 0; s < 8; ++s)
#pragma unroll
        for (int nt = 0; nt < 4; ++nt)
            w3r[s][nt] = *(const bf16x8*)(w3s + (s * 4 + q) * 2048 +
                                          (nb + nt * 16 + cl) * 8);

    // DMA staging geometry: wave w owns rows w*16..w*16+15. Instr i (0..7):
    // LDS base = w*8192 + i*1024, lane l -> +l*16; covers local row
    // ml = 2i + (l>>5), phys chunk pc = l&31, logical = pc ^ ml (bit4 kept).
    const int pc = lane & 31;
    const int rhi = lane >> 5;
    const int half = pc >> 4;

    int nds[8];
#define LOAD_IDX(tile)                                                       \
    _Pragma("unroll") for (int i = 0; i < 8; ++i) {                          \
        int ml = 2 * i + rhi;                                                \
        int e = (tile) * 64 + w * 16 + ml;                                   \
        int eo = half ? (NE + e) : e;                                        \
        int nd = i64f ? (int)ei64[eo] : ei32[eo];                            \
        nds[i] = nd < 0 ? 0 : (nd > NN - 1 ? NN - 1 : nd);                   \
    }
#define ISSUE_GLD(buf)                                                       \
    _Pragma("unroll") for (int i = 0; i < 8; ++i) {                          \
        int ml = 2 * i + rhi;                                                \
        int kc = (pc ^ ml) & 15;                                             \
        const unsigned short* gp = hbf + (long)nds[i] * 128 + kc * 8;        \
        char* lp = (char*)&A[buf][0] + w * 8192 + i * 1024;                  \
        GLD16(gp, lp);                                                       \
    }
#define MSTEP(s)                                                             \
    {                                                                        \
        bf16x8 a[4];                                                         \
        _Pragma("unroll") for (int mt = 0; mt < 4; ++mt)                     \
            a[mt] = *(const bf16x8*)(Ab + (mt * 16 + cl) * 256 +             \
                                     (((s) * 4 + q) ^ cl) * 8);              \
        _Pragma("unroll") for (int mt = 0; mt < 4; ++mt)                     \
            _Pragma("unroll") for (int nt = 0; nt < 4; ++nt)                 \
                acc[mt][nt] = __builtin_amdgcn_mfma_f32_16x16x32_bf16(       \
                    a[mt], w3r[s][nt], acc[mt][nt], 0, 0, 0);                \
    }

    // prologue: tile0 DMA'd into buf0; indices for tile1 prefetched
    int tile = blockIdx.x;
    LOAD_IDX(tile);
    ISSUE_GLD(0);
    {
        int n1 = tile + GRID_E;
        if (n1 < NT) LOAD_IDX(n1);
    }
    __syncthreads();   // drains DMA

    int buf = 0;
    for (;;) {
        const int next = tile + GRID_E;
        const bool has_next = next < NT;
        const bool has_next2 = next + GRID_E < NT;
        const unsigned short* Ab = &A[buf][0];

        f32x4 acc[4][4];
#pragma unroll
        for (int mt = 0; mt < 4; ++mt)
#pragma unroll
            for (int nt = 0; nt < 4; ++nt)
                acc[mt][nt] = (f32x4){b3v[nt], b3v[nt], b3v[nt], b3v[nt]};

        MSTEP(0) MSTEP(1) MSTEP(2) MSTEP(3)
        if (has_next) ISSUE_GLD(buf ^ 1);   // uses nds (next tile's nodes)
        if (has_next2) LOAD_IDX(next + GRID_E);  // prefetch following indices
        MSTEP(4) MSTEP(5) MSTEP(6) MSTEP(7)

        // epilogue: p = relu(acc).W4 per row; DPP row-reduce over cl.
        // row_shr accumulates toward the high lane: full sum at cl==15.
#pragma unroll
        for (int mt = 0; mt < 4; ++mt) {
            float pr[4];
#pragma unroll
            for (int r = 0; r < 4; ++r) {
                float s = 0.0f;
#pragma unroll
                for (int nt = 0; nt < 4; ++nt)
                    s += fmaxf(acc[mt][nt][r], 0.0f) * w4v[nt];
                pr[r] = row_reduce16(s);
            }
            if (cl == 15)   // lane q*16+15 holds rows mt*16+q*4+0..3
                *(f32x4*)&partial[buf][w][mt * 16 + q * 4] =
                    (f32x4){pr[0], pr[1], pr[2], pr[3]};
        }
        __syncthreads();   // also drains next tile's DMA + idx prefetch
        if (t < 64) {
            float logit = partial[buf][0][t] + partial[buf][1][t] +
                          partial[buf][2][t] + partial[buf][3][t] + b4v;
            out[tile * 64 + t] = 1.0f / (1.0f + __expf(-logit));
        }
        if (!has_next) break;
        tile = next;
        buf ^= 1;
    }
#undef LOAD_IDX
#undef ISSUE_GLD
#undef MSTEP
}

extern "C" void kernel_launch(void* const* d_in, const int* in_sizes, int n_in,
                              void* d_out, int out_size, void* d_ws, size_t ws_size,
                              hipStream_t stream) {
    const float* x  = (const float*)d_in[0];
    const void*  ei = d_in[1];
    const float* W1 = (const float*)d_in[2];
    const float* b1 = (const float*)d_in[3];
    const float* W2 = (const float*)d_in[4];
    const float* b2 = (const float*)d_in[5];
    const float* W3 = (const float*)d_in[6];
    const float* b3 = (const float*)d_in[7];
    const float* W4 = (const float*)d_in[8];
    const float* b4 = (const float*)d_in[9];

    char* ws = (char*)d_ws;
    int* flag            = (int*)ws;
    unsigned short* w1s  = (unsigned short*)(ws + 256);
    unsigned short* w2s  = (unsigned short*)(ws + 256 + 65536);
    unsigned short* w3s  = (unsigned short*)(ws + 256 + 131072);
    unsigned short* hbf  = (unsigned short*)(ws + 256 + 262144);

    prep_kernel<<<512, 256, 0, stream>>>(W1, W2, W3, ei, w1s, w2s, w3s, flag);
    node_enc<<<GRID_N, 256, 0, stream>>>(x, b1, b2, w1s, w2s, hbf);
    edge_mlp<<<GRID_E, 256, 0, stream>>>(ei, hbf, w3s, b3, W4, b4, flag, (float*)d_out);
}

// Round 8
// 328.066 us; speedup vs baseline: 1.4487x; 1.4487x over previous
//
#include <hip/hip_runtime.h>

// PPAModel: node encoder -> edge gather/concat -> edge MLP -> sigmoid
// IN=128, HID=256, OUT=128, N_NODES=100000, N_EDGES=1000000
//
// v8 ALGORITHMIC RESTRUCTURE: edge GEMM factorized away.
//   e@W3 = h_src@W3t + h_dst@W3b ;  h = relu1@W2
//   => precompute Wut=W2@W3t, Wvt=W2@W3b (prep), then per node
//      U = relu1@Wut + (b2@W3t + b3),  V = relu1@Wvt + b2@W3b   (node_uv)
//   => per edge: out = sigmoid( relu(U[src]+V[dst]) . W4 + b4 )  (edge_pred)
// Edge phase is now a pure streaming gather + VALU kernel: no MFMA, no LDS,
// no barriers; loads issue continuously (the structural fix for the ~25%
// load-duty-cycle that capped every edge-GEMM variant at >=247us).
//
// ws layout (~103.5 MB):
//   flag @ 0            w1s  @ 256      (64KB bf16 swizzled)
//   wuts @ 65792 (128KB)  wvts @ 196864 (128KB)
//   bu @ 327936 (1KB)     bv @ 328960 (1KB)
//   wutf @ 329984 (256KB) wvtf @ 592128 (256KB)
//   U @ 1048576 (51.2MB)  V @ 52248576 (51.2MB)

#define NN 100000
#define NE 1000000
#define NTN 1563      // node tiles
#define GRID_N 256
#define GRID_EP 1024

typedef __attribute__((ext_vector_type(8))) __bf16 bf16x8;
typedef __attribute__((ext_vector_type(4))) float f32x4;
typedef __attribute__((ext_vector_type(4))) unsigned short us4;

__device__ __forceinline__ unsigned short f2bf(float f) {
    unsigned u = __float_as_uint(f);
    return (unsigned short)((u + 0x7FFFu + ((u >> 16) & 1u)) >> 16);
}
__device__ __forceinline__ float bflo(unsigned w) {
    return __uint_as_float(w << 16);
}
__device__ __forceinline__ float bfhi(unsigned w) {
    return __uint_as_float(w & 0xffff0000u);
}

template <int CTRL>
__device__ __forceinline__ float dpp_add(float v) {
    return v + __int_as_float(__builtin_amdgcn_update_dpp(
                   0, __float_as_int(v), CTRL, 0xF, 0xF, true));
}
// sum over 16 lanes of a DPP row; valid at (lane&15)==15 (row_shr -> high lane)
__device__ __forceinline__ float row_reduce16(float v) {
    v = dpp_add<0x118>(v);
    v = dpp_add<0x114>(v);
    v = dpp_add<0x112>(v);
    v = dpp_add<0x111>(v);
    return v;
}

// ---------------- prep1: W1 swizzle, Wut/Wvt fp32, bu/bv, idx-dtype flag --
__global__ void prep1(const float* __restrict__ W1, const float* __restrict__ W2,
                      const float* __restrict__ W3, const float* __restrict__ b2,
                      const float* __restrict__ b3, const void* __restrict__ eidx,
                      unsigned short* __restrict__ w1s, float* __restrict__ wutf,
                      float* __restrict__ wvtf, float* __restrict__ bu,
                      float* __restrict__ bv, int* __restrict__ flag) {
    int t = blockIdx.x * blockDim.x + threadIdx.x;  // 131072 threads
    if (t < 32768) {  // W1 swizzle: K=128, N=256, [k/8][n][k%8]
        int k = t >> 8, n = t & 255;
        w1s[(k >> 3) * 2048 + n * 8 + (k & 7)] = f2bf(W1[t]);
    }
    if (t < 65536) {  // Wut[k][n] = sum_j W2[k][j] * W3[j][n], j<128
        int k = t >> 8, n = t & 255;
        float s = 0.0f;
        for (int j = 0; j < 128; ++j) s += W2[k * 128 + j] * W3[j * 256 + n];
        wutf[t] = s;
    } else {          // Wvt[k][n] = sum_j W2[k][j] * W3[128+j][n]
        int i = t - 65536;
        int k = i >> 8, n = i & 255;
        float s = 0.0f;
        for (int j = 0; j < 128; ++j) s += W2[k * 128 + j] * W3[(128 + j) * 256 + n];
        wvtf[i] = s;
    }
    if (t < 256) {    // bu = b3 + b2 @ W3t
        float s = b3[t];
        for (int j = 0; j < 128; ++j) s += b2[j] * W3[j * 256 + t];
        bu[t] = s;
    } else if (t < 512) {  // bv = b2 @ W3b
        int n = t - 256;
        float s = 0.0f;
        for (int j = 0; j < 128; ++j) s += b2[j] * W3[(128 + j) * 256 + n];
        bv[n] = s;
    }
    if (t == 0) {
        const unsigned* u = (const unsigned*)eidx;
        int all0 = 1;
        for (int i = 0; i < 32; ++i) all0 &= (u[2 * i + 1] == 0u);
        *flag = all0;
    }
}

// ---------------- prep2: swizzle Wut/Wvt fp32 -> bf16 MFMA layout ---------
__global__ void prep2(const float* __restrict__ wutf, const float* __restrict__ wvtf,
                      unsigned short* __restrict__ wuts, unsigned short* __restrict__ wvts) {
    int t = blockIdx.x * blockDim.x + threadIdx.x;  // 131072
    if (t < 65536) {
        int k = t >> 8, n = t & 255;
        wuts[(k >> 3) * 2048 + n * 8 + (k & 7)] = f2bf(wutf[t]);
    } else {
        int i = t - 65536;
        int k = i >> 8, n = i & 255;
        wvts[(k >> 3) * 2048 + n * 8 + (k & 7)] = f2bf(wvtf[i]);
    }
}

// ---------------- node_uv: x -> relu1 -> U,V (fused, 8 waves, K=256) ------
__global__ __launch_bounds__(512, 2) void node_uv(
    const float* __restrict__ x, const float* __restrict__ b1,
    const unsigned short* __restrict__ w1s, const unsigned short* __restrict__ wuts,
    const unsigned short* __restrict__ wvts, const float* __restrict__ bu,
    const float* __restrict__ bv, unsigned short* __restrict__ Ug,
    unsigned short* __restrict__ Vg) {
    __shared__ __align__(16) unsigned short A1[64 * 136];  // x tile bf16
    __shared__ __align__(16) unsigned short A2[64 * 264];  // relu1 tile bf16

    const int t = threadIdx.x, lane = t & 63, w = t >> 6;  // w: 0..7
    const int cl = lane & 15, q = lane >> 4;
    const int nb = w * 32;   // this wave's 32 N-cols (for all three GEMMs)

    // hoisted weight slices
    bf16x8 wutr[8][2], wvtr[8][2];
#pragma unroll
    for (int s = 0; s < 8; ++s)
#pragma unroll
        for (int nt = 0; nt < 2; ++nt) {
            wutr[s][nt] = *(const bf16x8*)(wuts + (s * 4 + q) * 2048 +
                                           (nb + nt * 16 + cl) * 8);
            wvtr[s][nt] = *(const bf16x8*)(wvts + (s * 4 + q) * 2048 +
                                           (nb + nt * 16 + cl) * 8);
        }
    float b1v[2], buv[2], bvv[2];
#pragma unroll
    for (int nt = 0; nt < 2; ++nt) {
        int n = nb + nt * 16 + cl;
        b1v[nt] = b1[n];
        buv[nt] = bu[n];
        bvv[nt] = bv[n];
    }

    for (int tile = blockIdx.x; tile < NTN; tile += GRID_N) {
        const int m0 = tile * 64;
        // stage x -> A1 bf16
        {
            const float4* x4 = (const float4*)x;
#pragma unroll
            for (int i = 0; i < 4; ++i) {
                int lin = i * 512 + t;
                int m = lin >> 5, c = lin & 31;
                int node = m0 + m;
                if (node > NN - 1) node = NN - 1;
                float4 v = x4[node * 32 + c];
                us4 b;
                b.x = f2bf(v.x); b.y = f2bf(v.y); b.z = f2bf(v.z); b.w = f2bf(v.w);
                *(us4*)(A1 + m * 136 + c * 4) = b;
            }
        }
        __syncthreads();

        // GEMM1: [64x128]x[128x256] (w1 slice loaded per tile; cheap L2 hit)
        f32x4 acc[4][2];
#pragma unroll
        for (int mt = 0; mt < 4; ++mt)
#pragma unroll
            for (int nt = 0; nt < 2; ++nt)
                acc[mt][nt] = (f32x4){b1v[nt], b1v[nt], b1v[nt], b1v[nt]};
#pragma unroll
        for (int s = 0; s < 4; ++s) {
            bf16x8 a[4], bw[2];
#pragma unroll
            for (int mt = 0; mt < 4; ++mt)
                a[mt] = *(const bf16x8*)(A1 + (mt * 16 + cl) * 136 + s * 32 + q * 8);
#pragma unroll
            for (int nt = 0; nt < 2; ++nt)
                bw[nt] = *(const bf16x8*)(w1s + (s * 4 + q) * 2048 +
                                          (nb + nt * 16 + cl) * 8);
#pragma unroll
            for (int mt = 0; mt < 4; ++mt)
#pragma unroll
                for (int nt = 0; nt < 2; ++nt)
                    acc[mt][nt] = __builtin_amdgcn_mfma_f32_16x16x32_bf16(
                        a[mt], bw[nt], acc[mt][nt], 0, 0, 0);
        }
        // relu -> A2
#pragma unroll
        for (int mt = 0; mt < 4; ++mt)
#pragma unroll
            for (int nt = 0; nt < 2; ++nt)
#pragma unroll
                for (int r = 0; r < 4; ++r) {
                    float v = fmaxf(acc[mt][nt][r], 0.0f);
                    A2[(mt * 16 + q * 4 + r) * 264 + nb + nt * 16 + cl] = f2bf(v);
                }
        __syncthreads();

        // GEMM U,V: [64x256]x[256x256] each; shared a-frags
        f32x4 accU[4][2], accV[4][2];
#pragma unroll
        for (int mt = 0; mt < 4; ++mt)
#pragma unroll
            for (int nt = 0; nt < 2; ++nt) {
                accU[mt][nt] = (f32x4){buv[nt], buv[nt], buv[nt], buv[nt]};
                accV[mt][nt] = (f32x4){bvv[nt], bvv[nt], bvv[nt], bvv[nt]};
            }
#pragma unroll
        for (int s = 0; s < 8; ++s) {
            bf16x8 a[4];
#pragma unroll
            for (int mt = 0; mt < 4; ++mt)
                a[mt] = *(const bf16x8*)(A2 + (mt * 16 + cl) * 264 + s * 32 + q * 8);
#pragma unroll
            for (int mt = 0; mt < 4; ++mt)
#pragma unroll
                for (int nt = 0; nt < 2; ++nt) {
                    accU[mt][nt] = __builtin_amdgcn_mfma_f32_16x16x32_bf16(
                        a[mt], wutr[s][nt], accU[mt][nt], 0, 0, 0);
                    accV[mt][nt] = __builtin_amdgcn_mfma_f32_16x16x32_bf16(
                        a[mt], wvtr[s][nt], accV[mt][nt], 0, 0, 0);
                }
        }
        // store U,V bf16
#pragma unroll
        for (int mt = 0; mt < 4; ++mt)
#pragma unroll
            for (int nt = 0; nt < 2; ++nt)
#pragma unroll
                for (int r = 0; r < 4; ++r) {
                    int node = m0 + mt * 16 + q * 4 + r;
                    if (node < NN) {
                        int col = nb + nt * 16 + cl;
                        Ug[node * 256 + col] = f2bf(accU[mt][nt][r]);
                        Vg[node * 256 + col] = f2bf(accV[mt][nt][r]);
                    }
                }
    }
}

// ---------------- edge_pred: streaming gather + VALU, 8 edges/wave-iter ---
#define TERM(uw, vw, wa, wb)                                     \
    (fmaxf(bflo(uw) + bflo(vw), 0.0f) * (wa) +                   \
     fmaxf(bfhi(uw) + bfhi(vw), 0.0f) * (wb))

__global__ __launch_bounds__(256, 4) void edge_pred(
    const void* __restrict__ eidx, const unsigned short* __restrict__ Ut,
    const unsigned short* __restrict__ Vt, const float* __restrict__ W4,
    const float* __restrict__ b4, const int* __restrict__ flag,
    float* __restrict__ out) {
    const int t = threadIdx.x, lane = t & 63;
    const int cl = lane & 15, g = lane >> 4;   // 4 edge-groups of 16 lanes
    const int gwid = (blockIdx.x * 256 + t) >> 6;
    const int nw = (GRID_EP * 256) >> 6;
    const bool i64f = (*flag != 0);
    const int* ei32 = (const int*)eidx;
    const long long* ei64 = (const long long*)eidx;

    float w4a[8], w4b[8];
#pragma unroll
    for (int j = 0; j < 8; ++j) {
        w4a[j] = W4[cl * 8 + j];
        w4b[j] = W4[128 + cl * 8 + j];
    }
    const float b4v = b4[0];

    for (int base = gwid * 8; base < NE; base += nw * 8) {
        const int eA = base + g, eB = base + 4 + g;
        int sA = i64f ? (int)ei64[eA] : ei32[eA];
        int dA = i64f ? (int)ei64[NE + eA] : ei32[NE + eA];
        int sB = i64f ? (int)ei64[eB] : ei32[eB];
        int dB = i64f ? (int)ei64[NE + eB] : ei32[NE + eB];
        sA = sA < 0 ? 0 : (sA > NN - 1 ? NN - 1 : sA);
        dA = dA < 0 ? 0 : (dA > NN - 1 ? NN - 1 : dA);
        sB = sB < 0 ? 0 : (sB > NN - 1 ? NN - 1 : sB);
        dB = dB < 0 ? 0 : (dB > NN - 1 ? NN - 1 : dB);

        const uint4* ua = (const uint4*)(Ut + (long)sA * 256) + cl;
        const uint4* va = (const uint4*)(Vt + (long)dA * 256) + cl;
        const uint4* ub = (const uint4*)(Ut + (long)sB * 256) + cl;
        const uint4* vb = (const uint4*)(Vt + (long)dB * 256) + cl;
        uint4 ua0 = ua[0], ua1 = ua[16];
        uint4 va0 = va[0], va1 = va[16];
        uint4 ub0 = ub[0], ub1 = ub[16];
        uint4 vb0 = vb[0], vb1 = vb[16];

        float accA =
            TERM(ua0.x, va0.x, w4a[0], w4a[1]) + TERM(ua0.y, va0.y, w4a[2], w4a[3]) +
            TERM(ua0.z, va0.z, w4a[4], w4a[5]) + TERM(ua0.w, va0.w, w4a[6], w4a[7]) +
            TERM(ua1.x, va1.x, w4b[0], w4b[1]) + TERM(ua1.y, va1.y, w4b[2], w4b[3]) +
            TERM(ua1.z, va1.z, w4b[4], w4b[5]) + TERM(ua1.w, va1.w, w4b[6], w4b[7]);
        float accB =
            TERM(ub0.x, vb0.x, w4a[0], w4a[1]) + TERM(ub0.y, vb0.y, w4a[2], w4a[3]) +
            TERM(ub0.z, vb0.z, w4a[4], w4a[5]) + TERM(ub0.w, vb0.w, w4a[6], w4a[7]) +
            TERM(ub1.x, vb1.x, w4b[0], w4b[1]) + TERM(ub1.y, vb1.y, w4b[2], w4b[3]) +
            TERM(ub1.z, vb1.z, w4b[4], w4b[5]) + TERM(ub1.w, vb1.w, w4b[6], w4b[7]);

        accA = row_reduce16(accA);
        accB = row_reduce16(accB);
        if (cl == 15) {
            out[eA] = 1.0f / (1.0f + __expf(-(accA + b4v)));
            out[eB] = 1.0f / (1.0f + __expf(-(accB + b4v)));
        }
    }
}

extern "C" void kernel_launch(void* const* d_in, const int* in_sizes, int n_in,
                              void* d_out, int out_size, void* d_ws, size_t ws_size,
                              hipStream_t stream) {
    const float* x  = (const float*)d_in[0];
    const void*  ei = d_in[1];
    const float* W1 = (const float*)d_in[2];
    const float* b1 = (const float*)d_in[3];
    const float* W2 = (const float*)d_in[4];
    const float* b2 = (const float*)d_in[5];
    const float* W3 = (const float*)d_in[6];
    const float* b3 = (const float*)d_in[7];
    const float* W4 = (const float*)d_in[8];
    const float* b4 = (const float*)d_in[9];

    char* ws = (char*)d_ws;
    int* flag            = (int*)ws;
    unsigned short* w1s  = (unsigned short*)(ws + 256);
    unsigned short* wuts = (unsigned short*)(ws + 65792);
    unsigned short* wvts = (unsigned short*)(ws + 196864);
    float* bu            = (float*)(ws + 327936);
    float* bv            = (float*)(ws + 328960);
    float* wutf          = (float*)(ws + 329984);
    float* wvtf          = (float*)(ws + 592128);
    unsigned short* Ug   = (unsigned short*)(ws + 1048576);
    unsigned short* Vg   = (unsigned short*)(ws + 52248576);

    prep1<<<512, 256, 0, stream>>>(W1, W2, W3, b2, b3, ei, w1s, wutf, wvtf, bu, bv, flag);
    prep2<<<512, 256, 0, stream>>>(wutf, wvtf, wuts, wvts);
    node_uv<<<GRID_N, 512, 0, stream>>>(x, b1, w1s, wuts, wvts, bu, bv, Ug, Vg);
    edge_pred<<<GRID_EP, 256, 0, stream>>>(ei, Ug, Vg, W4, b4, flag, (float*)d_out);
}